// Round 7
// baseline (9785.785 us; speedup 1.0000x reference)
//
#include <hip/hip_runtime.h>

#define BB   4
#define NN   256
#define TT   4096
#define DD   128      // SIM_DIM
#define LK   101      // LOOKUP
#define PADK 50
#define OD   128      // OUT_DIM
#define ROWS 164      // 64 + LK - 1 rows of halo'd proj window
#define RSTR 33       // band: row stride in float4 units (132 floats, +4 pad)
#define FSTR 260      // fs row stride floats
#define CPB  8        // pool chunks per block

// ---- amplification factors (measurement round; repeats are idempotent) ----
#define POOL_REP  6
#define PROJA_REP 96
#define PROJB_REP 96
#define BAND_REP  64

typedef float vfloat4 __attribute__((ext_vector_type(4)));

// ---------------- kernel 1: one-time weight transposes ----------------
__global__ __launch_bounds__(256) void transpose_w_kernel(
    const float* __restrict__ w_proj, const float* __restrict__ w_fc,
    float* __restrict__ w_t, float* __restrict__ wfc_t) {
  int idx = blockIdx.x * 256 + threadIdx.x;
  int stride = gridDim.x * 256;
  for (int i = idx; i < DD * NN; i += stride) {
    int d = i / NN, n = i - d * NN;
    w_t[n * DD + d] = w_proj[i];
  }
  for (int i = idx; i < OD * LK; i += stride) {
    int o = i / LK, j = i - o * LK;
    wfc_t[j * OD + o] = w_fc[i];
  }
}

// ---------------- kernel 2: pool (round-3 exact), amplified ----------------
__global__ __launch_bounds__(256) void pool_kernel(
    const float* __restrict__ x, float* __restrict__ feat) {
  __shared__ float part[2][768];
  int tid = threadIdx.x;
  for (int rep = 0; rep < POOL_REP; ++rep) {
    for (int c = 0; c < CPB; ++c) {
      size_t ck = (size_t)blockIdx.x * CPB + c;
      const vfloat4* x4 = (const vfloat4*)(x + ck * 3072);
      float* pb = part[c & 1];
#pragma unroll
      for (int p = 0; p < 3; ++p) {
        vfloat4 v = __builtin_nontemporal_load(&x4[p * 256 + tid]);
        pb[p * 256 + tid] = (v.x + v.y) + (v.z + v.w);
      }
      __syncthreads();
      if (tid < 64) {
        float s0 = 0.f, s1 = 0.f;
        const float* pp = pb + tid * 12;
#pragma unroll
        for (int i = 0; i < 6; ++i) { s0 += pp[i]; s1 += pp[6 + i]; }
        feat[ck * 64 + tid] = (s0 + s1) * (1.0f / 48.0f);
      }
    }
    __syncthreads();
  }
}

// ---------------- kernel 3a: projA = round-3 proj (64-t, (512,1)), amplified ----------------
__global__ __launch_bounds__(512, 1) void projA_kernel(
    const float* __restrict__ feat, const float* __restrict__ w_t,
    float* __restrict__ projn) {
  extern __shared__ float smemB[];
  float* fs = smemB;              // [64 t][260]
  float* ss = smemB + 64 * FSTR;  // [8 w][64 t]
  int b = blockIdx.x >> 6;
  int t0 = (blockIdx.x & 63) << 6;
  int tid = threadIdx.x;

  for (int rep = 0; rep < PROJA_REP; ++rep) {
    const float* fb = feat + ((size_t)b * NN) * TT + t0;
    for (int i = tid; i < NN * 64; i += 512) {
      int n = i >> 6, u = i & 63;
      fs[u * FSTR + n] = fb[(size_t)n * TT + u];
    }
    __syncthreads();

    int w = tid >> 6, lane = tid & 63;
    int d0u = __builtin_amdgcn_readfirstlane((tid >> 6) * 16);
    float acc[16];
#pragma unroll
    for (int k = 0; k < 16; ++k) acc[k] = 0.f;

    const float* fsr = fs + lane * FSTR;
    for (int n = 0; n < NN; n += 4) {
      float4 f = *(const float4*)(fsr + n);
      const float* wrow = w_t + n * DD + d0u;
#pragma unroll
      for (int q = 0; q < 4; ++q) {
        float fq = (q == 0) ? f.x : (q == 1) ? f.y : (q == 2) ? f.z : f.w;
        const float4* wv4 = (const float4*)(wrow + q * DD);
#pragma unroll
        for (int k = 0; k < 4; ++k) {
          float4 wv = wv4[k];
          acc[4 * k + 0] += wv.x * fq;
          acc[4 * k + 1] += wv.y * fq;
          acc[4 * k + 2] += wv.z * fq;
          acc[4 * k + 3] += wv.w * fq;
        }
      }
    }

    float s2 = 0.f;
#pragma unroll
    for (int k = 0; k < 16; ++k) s2 += acc[k] * acc[k];
    ss[w * 64 + lane] = s2;
    __syncthreads();
    float tot = 0.f;
#pragma unroll
    for (int q = 0; q < 8; ++q) tot += ss[q * 64 + lane];
    float inv = 1.0f / fmaxf(sqrtf(tot), 1e-12f);

    float4* po = (float4*)(projn + ((size_t)(b * TT + t0 + lane)) * DD + d0u);
#pragma unroll
    for (int k = 0; k < 4; ++k) {
      float4 o;
      o.x = acc[4 * k + 0] * inv;
      o.y = acc[4 * k + 1] * inv;
      o.z = acc[4 * k + 2] * inv;
      o.w = acc[4 * k + 3] * inv;
      po[k] = o;
    }
    __syncthreads();
  }
}

// ---------------- kernel 3b: projB = round-6 proj (32-t, (512,4)), amplified ----------------
__global__ __launch_bounds__(512, 4) void projB_kernel(
    const float* __restrict__ feat, const float* __restrict__ w_t,
    float* __restrict__ projn) {
  __shared__ float fs[32 * FSTR];
  __shared__ float ss[8 * 32];
  int b = blockIdx.x >> 7;
  int t0 = (blockIdx.x & 127) << 5;
  int tid = threadIdx.x;

  for (int rep = 0; rep < PROJB_REP; ++rep) {
    const float* fb = feat + ((size_t)b * NN) * TT + t0;
    for (int i = tid; i < NN * 32; i += 512) {
      int n = i >> 5, u = i & 31;
      fs[u * FSTR + n] = fb[(size_t)n * TT + u];
    }
    __syncthreads();

    int w = tid >> 6, lane = tid & 63;
    int t = lane & 31, h = lane >> 5;
    int d0 = __builtin_amdgcn_readfirstlane((tid >> 6) * 16);
    float acc[16];
#pragma unroll
    for (int k = 0; k < 16; ++k) acc[k] = 0.f;

    const float* fsr = fs + t * FSTR + h * 128;
    for (int c = 0; c < 32; ++c) {
      float4 f4 = *(const float4*)(fsr + 4 * c);
      const float* wrow = w_t + (h * 128 + 4 * c) * DD + d0;
#pragma unroll
      for (int q = 0; q < 4; ++q) {
        float fq = (q == 0) ? f4.x : (q == 1) ? f4.y : (q == 2) ? f4.z : f4.w;
        const float4* wv4 = (const float4*)(wrow + q * DD);
#pragma unroll
        for (int k = 0; k < 4; ++k) {
          float4 wv = wv4[k];
          acc[4 * k + 0] += wv.x * fq;
          acc[4 * k + 1] += wv.y * fq;
          acc[4 * k + 2] += wv.z * fq;
          acc[4 * k + 3] += wv.w * fq;
        }
      }
    }
#pragma unroll
    for (int k = 0; k < 16; ++k) acc[k] += __shfl_xor(acc[k], 32, 64);

    float s2 = 0.f;
#pragma unroll
    for (int k = 0; k < 16; ++k) s2 += acc[k] * acc[k];
    if (h == 0) ss[w * 32 + t] = s2;
    __syncthreads();
    float tot = 0.f;
#pragma unroll
    for (int q = 0; q < 8; ++q) tot += ss[q * 32 + t];
    float inv = 1.0f / fmaxf(sqrtf(tot), 1e-12f);

    float4* po = (float4*)(projn + ((size_t)(b * TT + t0 + t)) * DD + d0 + h * 8);
#pragma unroll
    for (int k = 0; k < 2; ++k) {
      int kb = h * 8 + k * 4;
      float4 o;
      o.x = acc[kb + 0] * inv;
      o.y = acc[kb + 1] * inv;
      o.z = acc[kb + 2] * inv;
      o.w = acc[kb + 3] * inv;
      po[k] = o;
    }
    __syncthreads();
  }
}

// ---------------- kernel 4: band_fc (round-6, XCD swizzle, 4 chains), amplified ----------------
__global__ __launch_bounds__(512, 1) void band_fc_kernel(
    const float* __restrict__ projn, const float* __restrict__ wfc_t,
    const float* __restrict__ b_fc, float* __restrict__ out) {
  extern __shared__ float4 smemC[];
  float4* p4 = smemC;                            // [ROWS][RSTR]
  float* band = (float*)(smemC + ROWS * RSTR);   // [64][101]
  int bid = (blockIdx.x & 7) * 32 + (blockIdx.x >> 3);
  int b = bid >> 6;
  int t0 = (bid & 63) << 6;
  int tid = threadIdx.x;

  for (int rep = 0; rep < BAND_REP; ++rep) {
    const float4* pg = (const float4*)projn;
    for (int i = tid; i < ROWS * 32; i += 512) {
      int r = i >> 5, c = i & 31;
      int t = t0 + r - PADK;
      float4 v = make_float4(0.f, 0.f, 0.f, 0.f);
      if (t >= 0 && t < TT) v = pg[(((size_t)b * TT + t) << 5) + c];
      p4[r * RSTR + c] = v;
    }
    __syncthreads();

    int w = tid >> 6, tt = tid & 63;

    float4 own[32];
#pragma unroll
    for (int c = 0; c < 32; ++c) own[c] = p4[(tt + PADK) * RSTR + c];

    int s0 = w * 21;
    int sEnd = (s0 + 21 < ROWS) ? (s0 + 21) : ROWS;
    for (int s = s0; s < sEnd; ++s) {
      float a0 = 0.f, a1 = 0.f, a2 = 0.f, a3 = 0.f;
#pragma unroll
      for (int c = 0; c < 32; ++c) {
        float4 ov = p4[s * RSTR + c];
        a0 += own[c].x * ov.x;
        a1 += own[c].y * ov.y;
        a2 += own[c].z * ov.z;
        a3 += own[c].w * ov.w;
      }
      int j = s - tt;
      if (j >= 0 && j < LK) band[tt * LK + j] = (a0 + a1) + (a2 + a3);
    }
    __syncthreads();

    int o0u = __builtin_amdgcn_readfirstlane((tid >> 6) * 16);
    float acc[16];
    const float4* bf4 = (const float4*)(b_fc + o0u);
#pragma unroll
    for (int k = 0; k < 4; ++k) {
      float4 bv = bf4[k];
      acc[4 * k + 0] = bv.x; acc[4 * k + 1] = bv.y;
      acc[4 * k + 2] = bv.z; acc[4 * k + 3] = bv.w;
    }
#pragma unroll 2
    for (int j = 0; j < LK; ++j) {
      float bv = band[tt * LK + j];
      const float4* wr = (const float4*)(wfc_t + j * OD + o0u);
#pragma unroll
      for (int k = 0; k < 4; ++k) {
        float4 wv = wr[k];
        acc[4 * k + 0] += wv.x * bv;
        acc[4 * k + 1] += wv.y * bv;
        acc[4 * k + 2] += wv.z * bv;
        acc[4 * k + 3] += wv.w * bv;
      }
    }
    float4* og = (float4*)(out + ((size_t)(b * TT + t0 + tt)) * OD + o0u);
#pragma unroll
    for (int k = 0; k < 4; ++k) {
      float4 o;
      o.x = fmaxf(acc[4 * k + 0], 0.f);
      o.y = fmaxf(acc[4 * k + 1], 0.f);
      o.z = fmaxf(acc[4 * k + 2], 0.f);
      o.w = fmaxf(acc[4 * k + 3], 0.f);
      og[k] = o;
    }
    __syncthreads();
  }
}

extern "C" void kernel_launch(void* const* d_in, const int* in_sizes, int n_in,
                              void* d_out, int out_size, void* d_ws, size_t ws_size,
                              hipStream_t stream) {
  const float* x      = (const float*)d_in[0];
  const float* w_proj = (const float*)d_in[1];
  const float* w_fc   = (const float*)d_in[2];
  const float* b_fc   = (const float*)d_in[3];
  float* out = (float*)d_out;

  char* ws = (char*)d_ws;
  float* feat  = (float*)ws;                                    // B*N*T f32  = 16,777,216 B
  float* projn = (float*)(ws + 16777216);                       // B*T*D f32  =  8,388,608 B
  float* w_t   = (float*)(ws + 16777216 + 8388608);             // N*D f32    =    131,072 B
  float* wfc_t = (float*)(ws + 16777216 + 8388608 + 131072);    // LK*OD f32  =     51,712 B

  size_t smB = (size_t)(64 * FSTR + 8 * 64) * sizeof(float);                           // 68,608 B
  size_t smC = (size_t)ROWS * RSTR * sizeof(float4) + (size_t)64 * LK * sizeof(float); // 112,448 B
  (void)hipFuncSetAttribute((const void*)projA_kernel,
                      hipFuncAttributeMaxDynamicSharedMemorySize, (int)smB);
  (void)hipFuncSetAttribute((const void*)band_fc_kernel,
                      hipFuncAttributeMaxDynamicSharedMemorySize, (int)smC);

  transpose_w_kernel<<<64, 256, 0, stream>>>(w_proj, w_fc, w_t, wfc_t);
  pool_kernel<<<(BB * NN * TT) / (64 * CPB), 256, 0, stream>>>(x, feat);
  projA_kernel<<<BB * (TT / 64), 512, smB, stream>>>(feat, w_t, projn);
  projB_kernel<<<BB * (TT / 32), 512, 0, stream>>>(feat, w_t, projn);
  band_fc_kernel<<<BB * (TT / 64), 512, smC, stream>>>(projn, wfc_t, b_fc, out);
}

// Round 8
// 219.789 us; speedup vs baseline: 44.5235x; 44.5235x over previous
//
#include <hip/hip_runtime.h>

#define BB   4
#define NN   256
#define TT   4096
#define DD   128      // SIM_DIM
#define LK   101      // LOOKUP
#define PADK 50
#define OD   128      // OUT_DIM
#define ROWS 164      // 64 + LK - 1 rows of halo'd proj window
#define RSTR 33       // band: row stride in float4 units (132 floats, +4 pad)
#define CPB  8        // pool chunks per block
#define FS_STR 68     // proj fs row stride (64 t + 4 pad)
#define WB_STR 132    // proj wbuf row stride (128 d + 4 pad)

typedef float vfloat4 __attribute__((ext_vector_type(4)));

// ---------------- kernel 1: one-time weight transposes ----------------
__global__ __launch_bounds__(256) void transpose_w_kernel(
    const float* __restrict__ w_proj, const float* __restrict__ w_fc,
    float* __restrict__ w_t, float* __restrict__ wfc_t) {
  int idx = blockIdx.x * 256 + threadIdx.x;
  int stride = gridDim.x * 256;
  for (int i = idx; i < DD * NN; i += stride) {
    int d = i / NN, n = i - d * NN;
    w_t[n * DD + d] = w_proj[i];
  }
  for (int i = idx; i < OD * LK; i += stride) {
    int o = i / LK, j = i - o * LK;
    wfc_t[j * OD + o] = w_fc[i];
  }
}

// ---------------- kernel 2: spatial mean-pool (round-3 exact, HBM-bound) ----------------
__global__ __launch_bounds__(256) void pool_kernel(
    const float* __restrict__ x, float* __restrict__ feat) {
  __shared__ float part[2][768];
  int tid = threadIdx.x;
  for (int c = 0; c < CPB; ++c) {
    size_t ck = (size_t)blockIdx.x * CPB + c;
    const vfloat4* x4 = (const vfloat4*)(x + ck * 3072);
    float* pb = part[c & 1];
#pragma unroll
    for (int p = 0; p < 3; ++p) {
      vfloat4 v = __builtin_nontemporal_load(&x4[p * 256 + tid]);
      pb[p * 256 + tid] = (v.x + v.y) + (v.z + v.w);
    }
    __syncthreads();
    if (tid < 64) {
      float s0 = 0.f, s1 = 0.f;
      const float* pp = pb + tid * 12;
#pragma unroll
      for (int i = 0; i < 6; ++i) { s0 += pp[i]; s1 += pp[6 + i]; }
      feat[ck * 64 + tid] = (s0 + s1) * (1.0f / 48.0f);
    }
  }
}

// ---------------- kernel 3: projection + L2 normalize (v3: LDS weights, 4t x 4d tile) ----------------
// 256 blocks (b, 64-t tile) x 512 thr, ~103 KB dynamic LDS -> 1 block/CU (8 waves).
// Weights staged block-wide into LDS (4 chunks of 64 n): zero redundant L2 traffic.
// Thread (tt=tid>>5, td=tid&31) owns t in [4tt,4tt+4) x d in [4td,4td+4).
// Per n: 1 feat ds_read_b128 (2 distinct/wave) + 1 weight ds_read_b128 (32 distinct) + 16 FMA.
__global__ __launch_bounds__(512, 1) void proj_kernel(
    const float* __restrict__ feat, const float* __restrict__ w_t,
    float* __restrict__ projn) {
  extern __shared__ float smemP[];
  float* fs   = smemP;              // [256 n][68]  feat tile, n-major
  float* wbuf = smemP + NN * FS_STR; // [64 n][132] weight chunk
  int b = blockIdx.x >> 6;
  int t0 = (blockIdx.x & 63) << 6;
  int tid = threadIdx.x;
  int td = tid & 31, tt = tid >> 5;

  float acc[4][4];
#pragma unroll
  for (int i = 0; i < 4; ++i)
#pragma unroll
    for (int j = 0; j < 4; ++j) acc[i][j] = 0.f;

  for (int c = 0; c < 4; ++c) {
    if (c) __syncthreads();   // previous chunk's compute done before wbuf overwrite
    // stage weight chunk: 64 n x 128 d
#pragma unroll
    for (int k = 0; k < 4; ++k) {
      int slot = tid + k * 512;            // 0..2047
      int n = slot >> 5, d4 = slot & 31;
      *(float4*)(wbuf + n * WB_STR + d4 * 4) =
          *(const float4*)(w_t + (size_t)(c * 64 + n) * DD + d4 * 4);
    }
    if (c == 0) {
      // stage feat tile once: 256 n x 64 t
#pragma unroll
      for (int k = 0; k < 8; ++k) {
        int slot = tid + k * 512;          // 0..4095
        int n = slot >> 4, t4 = slot & 15;
        *(float4*)(fs + n * FS_STR + t4 * 4) =
            *(const float4*)(feat + ((size_t)(b * NN + n)) * TT + t0 + t4 * 4);
      }
    }
    __syncthreads();

    const float* fp = fs + (c * 64) * FS_STR + tt * 4;
    const float* wp = wbuf + td * 4;
#pragma unroll 4
    for (int n = 0; n < 64; ++n) {
      float4 f = *(const float4*)(fp + n * FS_STR);
      float4 wv = *(const float4*)(wp + n * WB_STR);
      float fa[4] = {f.x, f.y, f.z, f.w};
#pragma unroll
      for (int i = 0; i < 4; ++i) {
        acc[i][0] += fa[i] * wv.x;
        acc[i][1] += fa[i] * wv.y;
        acc[i][2] += fa[i] * wv.z;
        acc[i][3] += fa[i] * wv.w;
      }
    }
  }

  // L2 norm per t-row: reduce acc^2 across the 32 td-lanes (same wave half)
  float s[4];
#pragma unroll
  for (int i = 0; i < 4; ++i)
    s[i] = acc[i][0] * acc[i][0] + acc[i][1] * acc[i][1] +
           acc[i][2] * acc[i][2] + acc[i][3] * acc[i][3];
#pragma unroll
  for (int m = 1; m < 32; m <<= 1) {
#pragma unroll
    for (int i = 0; i < 4; ++i) s[i] += __shfl_xor(s[i], m, 64);
  }
#pragma unroll
  for (int i = 0; i < 4; ++i) {
    float inv = 1.0f / fmaxf(sqrtf(s[i]), 1e-12f);
    float4 o;
    o.x = acc[i][0] * inv; o.y = acc[i][1] * inv;
    o.z = acc[i][2] * inv; o.w = acc[i][3] * inv;
    *(float4*)(projn + ((size_t)(b * TT + t0 + tt * 4 + i)) * DD + td * 4) = o;
  }
}

// ---------------- kernel 4: banded cosine sims + FC + ReLU (round-5 exact) ----------------
__global__ __launch_bounds__(512, 1) void band_fc_kernel(
    const float* __restrict__ projn, const float* __restrict__ wfc_t,
    const float* __restrict__ b_fc, float* __restrict__ out) {
  extern __shared__ float4 smemC[];
  float4* p4 = smemC;                            // [ROWS][RSTR]
  float* band = (float*)(smemC + ROWS * RSTR);   // [64][101]
  int b = blockIdx.x >> 6;
  int t0 = (blockIdx.x & 63) << 6;
  int tid = threadIdx.x;

  const float4* pg = (const float4*)projn;
  for (int i = tid; i < ROWS * 32; i += 512) {
    int r = i >> 5, c = i & 31;
    int t = t0 + r - PADK;
    float4 v = make_float4(0.f, 0.f, 0.f, 0.f);
    if (t >= 0 && t < TT) v = pg[(((size_t)b * TT + t) << 5) + c];
    p4[r * RSTR + c] = v;
  }
  __syncthreads();

  int w = tid >> 6, tt = tid & 63;

  float4 own[32];
#pragma unroll
  for (int c = 0; c < 32; ++c) own[c] = p4[(tt + PADK) * RSTR + c];

  int s0 = w * 21;
  int sEnd = (s0 + 21 < ROWS) ? (s0 + 21) : ROWS;
  for (int s = s0; s < sEnd; ++s) {
    float a0 = 0.f, a1 = 0.f, a2 = 0.f, a3 = 0.f;  // 4 independent chains
#pragma unroll
    for (int c = 0; c < 32; ++c) {
      float4 ov = p4[s * RSTR + c];   // wave-uniform -> LDS broadcast
      a0 += own[c].x * ov.x;
      a1 += own[c].y * ov.y;
      a2 += own[c].z * ov.z;
      a3 += own[c].w * ov.w;
    }
    int j = s - tt;
    if (j >= 0 && j < LK) band[tt * LK + j] = (a0 + a1) + (a2 + a3);
  }
  __syncthreads();

  int o0u = __builtin_amdgcn_readfirstlane((tid >> 6) * 16);
  float acc[16];
  const float4* bf4 = (const float4*)(b_fc + o0u);
#pragma unroll
  for (int k = 0; k < 4; ++k) {
    float4 bv = bf4[k];
    acc[4 * k + 0] = bv.x; acc[4 * k + 1] = bv.y;
    acc[4 * k + 2] = bv.z; acc[4 * k + 3] = bv.w;
  }
#pragma unroll 2
  for (int j = 0; j < LK; ++j) {
    float bv = band[tt * LK + j];                 // gcd(101,32)=1: conflict-free
    const float4* wr = (const float4*)(wfc_t + j * OD + o0u);  // uniform
#pragma unroll
    for (int k = 0; k < 4; ++k) {
      float4 wv = wr[k];
      acc[4 * k + 0] += wv.x * bv;
      acc[4 * k + 1] += wv.y * bv;
      acc[4 * k + 2] += wv.z * bv;
      acc[4 * k + 3] += wv.w * bv;
    }
  }
  float4* og = (float4*)(out + ((size_t)(b * TT + t0 + tt)) * OD + o0u);
#pragma unroll
  for (int k = 0; k < 4; ++k) {
    float4 o;
    o.x = fmaxf(acc[4 * k + 0], 0.f);
    o.y = fmaxf(acc[4 * k + 1], 0.f);
    o.z = fmaxf(acc[4 * k + 2], 0.f);
    o.w = fmaxf(acc[4 * k + 3], 0.f);
    og[k] = o;
  }
}

extern "C" void kernel_launch(void* const* d_in, const int* in_sizes, int n_in,
                              void* d_out, int out_size, void* d_ws, size_t ws_size,
                              hipStream_t stream) {
  const float* x      = (const float*)d_in[0];
  const float* w_proj = (const float*)d_in[1];
  const float* w_fc   = (const float*)d_in[2];
  const float* b_fc   = (const float*)d_in[3];
  float* out = (float*)d_out;

  char* ws = (char*)d_ws;
  float* feat  = (float*)ws;                                    // B*N*T f32  = 16,777,216 B
  float* projn = (float*)(ws + 16777216);                       // B*T*D f32  =  8,388,608 B
  float* w_t   = (float*)(ws + 16777216 + 8388608);             // N*D f32    =    131,072 B
  float* wfc_t = (float*)(ws + 16777216 + 8388608 + 131072);    // LK*OD f32  =     51,712 B

  size_t smP = (size_t)(NN * FS_STR + 64 * WB_STR) * sizeof(float);                    // 103,424 B
  size_t smC = (size_t)ROWS * RSTR * sizeof(float4) + (size_t)64 * LK * sizeof(float); // 112,448 B
  (void)hipFuncSetAttribute((const void*)proj_kernel,
                      hipFuncAttributeMaxDynamicSharedMemorySize, (int)smP);
  (void)hipFuncSetAttribute((const void*)band_fc_kernel,
                      hipFuncAttributeMaxDynamicSharedMemorySize, (int)smC);

  transpose_w_kernel<<<64, 256, 0, stream>>>(w_proj, w_fc, w_t, wfc_t);
  pool_kernel<<<(BB * NN * TT) / (64 * CPB), 256, 0, stream>>>(x, feat);
  proj_kernel<<<BB * (TT / 64), 512, smP, stream>>>(feat, w_t, projn);
  band_fc_kernel<<<BB * (TT / 64), 512, smC, stream>>>(projn, wfc_t, b_fc, out);
}